// Round 3
// baseline (150.409 us; speedup 1.0000x reference)
//
#include <hip/hip_runtime.h>

#define NUM_CLASSES 5
#define BATCH 4
#define NPB (64 * 256 * 256)            // voxels per batch = 4,194,304
#define VEC_PER_BATCH (NPB / 4)         // int4 vectors per batch = 1,048,576
#define THREADS 256
#define VECS 16                         // int4 per thread per input (64 voxels)
#define BLOCKS_X (VEC_PER_BATCH / (THREADS * VECS))   // 256 per batch
#define SLOTS 15                        // 5 pred, 5 targ, 5 inter
#define PSTRIDE 16                      // padded per-block partial stride

// Round-3 theory: rounds 0-2 all had <=1 load in flight per wave (VGPR_Count
// 32/32/52 vs the 64+ data regs the source asked for) because LLVM serializes
// plain loads at IR level before sched_barrier can pin anything. Replay rows
// with FETCH_SIZE~0 (fully L3-resident) run at the same 45.8us -> latency-bound,
// not BW-bound. Fix: inline-asm global_load_dwordx4 + counted s_waitcnt vmcnt.
// Steady state: 16 loads (16 KB) per wave in flight; wait vmcnt(14), consume
// oldest pair, issue replacement pair. Consumes are data-dependent on the
// vmcnt asm's "+v"-tied outputs, so they cannot be hoisted above the wait.
// No other vmem instruction exists in the loop region (LDS/shuffle are DS ops,
// partial store is after the final vmcnt(0)), so the counts are exact.

typedef int v4i __attribute__((ext_vector_type(4)));

#define GLOAD(Q, VOFF, SBASE) \
  asm volatile("global_load_dwordx4 %0, %1, %2" : "=v"(Q) : "v"(VOFF), "s"(SBASE))

#define WAITP(N, P, T) \
  asm volatile("s_waitcnt vmcnt(" #N ")" : "+v"(P), "+v"(T))

__global__ __launch_bounds__(THREADS, 4) void dice_count_kernel(
    const int* __restrict__ pred, const int* __restrict__ targ,
    unsigned int* __restrict__ partial) {
  const int b = blockIdx.y;
  // Wave-uniform 64-bit bases (SALU); per-thread part lives in the 32-bit voffset.
  const unsigned long long pB = (unsigned long long)(
      pred + (long long)b * NPB + (long long)blockIdx.x * (THREADS * VECS * 4));
  const unsigned long long tB = (unsigned long long)(
      targ + (long long)b * NPB + (long long)blockIdx.x * (THREADS * VECS * 4));

  // Byte offsets: thread t, pair k -> t*16 + k*4096 (coalesced: lane stride 16B).
  unsigned vo[VECS];
#pragma unroll
  for (int k = 0; k < VECS; ++k) vo[k] = threadIdx.x * 16u + (unsigned)k * 4096u;

  v4i qp[VECS], qt[VECS];

  // Packed per-lane counters: class c in bits [6c, 6c+6).
  // acc*0 <- pairs 0..7 (32 voxels <= 63/class), acc*1 <- pairs 8..15.
  unsigned accP0 = 0, accP1 = 0, accT0 = 0, accT1 = 0, accI0 = 0, accI1 = 0;

#define ACC_ELEM(PE, TE, AP, AT, AI)                   \
    {                                                  \
      const unsigned op = 1u << (6u * (unsigned)(PE)); \
      AP += op;                                        \
      AT += 1u << (6u * (unsigned)(TE));               \
      AI += ((PE) == (TE)) ? op : 0u;                  \
    }
#define CONS1(PV, TV, AP, AT, AI)                      \
    ACC_ELEM(PV[0], TV[0], AP, AT, AI)                 \
    ACC_ELEM(PV[1], TV[1], AP, AT, AI)                 \
    ACC_ELEM(PV[2], TV[2], AP, AT, AI)                 \
    ACC_ELEM(PV[3], TV[3], AP, AT, AI)

#define ISSUE(K)  GLOAD(qp[K], vo[K], pB); GLOAD(qt[K], vo[K], tB)
#define STEP(K, N, AP, AT, AI) \
    WAITP(N, qp[K], qt[K]);    \
    CONS1(qp[K], qt[K], AP, AT, AI)

  // Prologue: fill the pipe with 16 loads (pairs 0..7).
  ISSUE(0); ISSUE(1); ISSUE(2); ISSUE(3);
  ISSUE(4); ISSUE(5); ISSUE(6); ISSUE(7);
  // Steady state: consume oldest pair (vmcnt(14) = 14 younger loads still
  // outstanding), refill with the pair 8 positions ahead.
  STEP(0, 14, accP0, accT0, accI0); ISSUE(8);
  STEP(1, 14, accP0, accT0, accI0); ISSUE(9);
  STEP(2, 14, accP0, accT0, accI0); ISSUE(10);
  STEP(3, 14, accP0, accT0, accI0); ISSUE(11);
  STEP(4, 14, accP0, accT0, accI0); ISSUE(12);
  STEP(5, 14, accP0, accT0, accI0); ISSUE(13);
  STEP(6, 14, accP0, accT0, accI0); ISSUE(14);
  STEP(7, 14, accP0, accT0, accI0); ISSUE(15);
  // Drain.
  STEP(8,  14, accP1, accT1, accI1);
  STEP(9,  12, accP1, accT1, accI1);
  STEP(10, 10, accP1, accT1, accI1);
  STEP(11,  8, accP1, accT1, accI1);
  STEP(12,  6, accP1, accT1, accI1);
  STEP(13,  4, accP1, accT1, accI1);
  STEP(14,  2, accP1, accT1, accI1);
  STEP(15,  0, accP1, accT1, accI1);

  // Unpack 6-bit fields of both halves -> 16-bit pairs (per-field <= 64).
#define UNPACK(A0, A1, R01, R23, R4)                                     \
  unsigned R01 = ((A0 & 63u) + (A1 & 63u)) |                             \
                 ((((A0 >> 6) & 63u) + ((A1 >> 6) & 63u)) << 16);        \
  unsigned R23 = (((A0 >> 12) & 63u) + ((A1 >> 12) & 63u)) |             \
                 ((((A0 >> 18) & 63u) + ((A1 >> 18) & 63u)) << 16);      \
  unsigned R4 = ((A0 >> 24) & 63u) + ((A1 >> 24) & 63u);
  UNPACK(accP0, accP1, p01, p23, p4r)
  UNPACK(accT0, accT1, t01, t23, t4r)
  UNPACK(accI0, accI1, i01, i23, i4r)

  // 64-lane butterfly; 16-bit fields hold <= 64*64 = 4096, no overflow.
#pragma unroll
  for (int off = 32; off >= 1; off >>= 1) {
    p01 += (unsigned)__shfl_xor((int)p01, off);
    p23 += (unsigned)__shfl_xor((int)p23, off);
    p4r += (unsigned)__shfl_xor((int)p4r, off);
    t01 += (unsigned)__shfl_xor((int)t01, off);
    t23 += (unsigned)__shfl_xor((int)t23, off);
    t4r += (unsigned)__shfl_xor((int)t4r, off);
    i01 += (unsigned)__shfl_xor((int)i01, off);
    i23 += (unsigned)__shfl_xor((int)i23, off);
    i4r += (unsigned)__shfl_xor((int)i4r, off);
  }

  __shared__ unsigned int s[SLOTS];
  if (threadIdx.x < SLOTS) s[threadIdx.x] = 0;
  __syncthreads();

  if ((threadIdx.x & 63) == 0) {
    atomicAdd(&s[0], p01 & 0xFFFFu);
    atomicAdd(&s[1], p01 >> 16);
    atomicAdd(&s[2], p23 & 0xFFFFu);
    atomicAdd(&s[3], p23 >> 16);
    atomicAdd(&s[4], p4r);
    atomicAdd(&s[5], t01 & 0xFFFFu);
    atomicAdd(&s[6], t01 >> 16);
    atomicAdd(&s[7], t23 & 0xFFFFu);
    atomicAdd(&s[8], t23 >> 16);
    atomicAdd(&s[9], t4r);
    atomicAdd(&s[10], i01 & 0xFFFFu);
    atomicAdd(&s[11], i01 >> 16);
    atomicAdd(&s[12], i23 & 0xFFFFu);
    atomicAdd(&s[13], i23 >> 16);
    atomicAdd(&s[14], i4r);
  }
  __syncthreads();

  if (threadIdx.x < SLOTS)
    partial[(b * BLOCKS_X + blockIdx.x) * PSTRIDE + threadIdx.x] = s[threadIdx.x];
}

__global__ __launch_bounds__(256) void dice_final_kernel(
    const unsigned int* __restrict__ partial, float* __restrict__ out) {
  // 240 active threads: t = (bb*SLOTS + slot)*4 + q; q splits the 256 blocks
  // of one batch into quarters for parallel latency hiding.
  __shared__ unsigned int red[BATCH * SLOTS][4];
  const int t = threadIdx.x;
  if (t < BATCH * SLOTS * 4) {
    const int q = t & 3;
    const int s = (t >> 2) % SLOTS;
    const int bb = (t >> 2) / SLOTS;
    unsigned int sum = 0;
    for (int j = q * (BLOCKS_X / 4); j < (q + 1) * (BLOCKS_X / 4); ++j)
      sum += partial[(bb * BLOCKS_X + j) * PSTRIDE + s];
    red[(t >> 2)][q] = sum;
  }
  __syncthreads();
  if (t < NUM_CLASSES) {
    float acc = 0.0f;
#pragma unroll
    for (int bb = 0; bb < BATCH; ++bb) {
      const int ip = bb * SLOTS + t;
      const int it = bb * SLOTS + 5 + t;
      const int ii = bb * SLOTS + 10 + t;
      const float ps = (float)(red[ip][0] + red[ip][1] + red[ip][2] + red[ip][3]);
      const float ts = (float)(red[it][0] + red[it][1] + red[it][2] + red[it][3]);
      const float is = (float)(red[ii][0] + red[ii][1] + red[ii][2] + red[ii][3]);
      float num = 2.0f * is;
      float den = ps + ts;
      if (den == 0.0f) { num = 1.0f; den = 1.0f; }
      acc += num / den;
    }
    out[t] = acc * (1.0f / BATCH);
  }
}

extern "C" void kernel_launch(void* const* d_in, const int* in_sizes, int n_in,
                              void* d_out, int out_size, void* d_ws, size_t ws_size,
                              hipStream_t stream) {
  const int* pred = (const int*)d_in[0];
  const int* targ = (const int*)d_in[1];
  float* out = (float*)d_out;
  unsigned int* partial = (unsigned int*)d_ws;

  dim3 grid(BLOCKS_X, BATCH);
  dice_count_kernel<<<grid, THREADS, 0, stream>>>(pred, targ, partial);
  dice_final_kernel<<<1, 256, 0, stream>>>(partial, out);
}

// Round 5
// 149.469 us; speedup vs baseline: 1.0063x; 1.0063x over previous
//
#include <hip/hip_runtime.h>

#define NUM_CLASSES 5
#define BATCH 4
#define NPB (64 * 256 * 256)            // voxels per batch = 4,194,304
#define VEC_PER_BATCH (NPB / 4)         // int4 vectors per batch = 1,048,576
#define THREADS 256
#define VECS 16                         // int4 per thread per input (64 voxels)
#define BLOCKS_X (VEC_PER_BATCH / (THREADS * VECS))   // 256 per batch
#define SLOTS 15                        // 5 pred, 5 targ, 5 inter
#define PSTRIDE 16                      // padded per-block partial stride

// Round-4 theory (resubmitted verbatim after broker timeout): rounds 0-3
// never achieved >1-2 loads in flight per wave. Round 3's 16-deep asm
// pipeline needed ~100 live VGPRs under a 128 cap and the RA spilled the asm
// outputs (spill reads the loaded reg -> vmcnt(0) right after issue ->
// serialized again; VGPR_Count=40 is the proof). Per-SIMD arithmetic: 128
// wave-loads in 109k cycles = 1 load / ~850 cy / SIMD = serialized at
// HBM/L3 latency. This round: depth-8 pipeline rotating through 4 NAMED
// buffer pairs (32 data VGPRs live, ~60 total) under a 256-VGPR cap
// (__launch_bounds__(256,2)) -- spill-proof by construction. Counted
// s_waitcnt vmcnt(6) steady state; consumes are data-dependent on the
// wait's "+v"-tied outputs so they cannot hoist. No other VMEM op in the
// region -> counts exact.

typedef int v4i __attribute__((ext_vector_type(4)));

#define GLOAD(Q, VOFF, SBASE) \
  asm volatile("global_load_dwordx4 %0, %1, %2" : "=v"(Q) : "v"(VOFF), "s"(SBASE))

#define WAITP(N, P, T) \
  asm volatile("s_waitcnt vmcnt(" #N ")" : "+v"(P), "+v"(T))

__global__ __launch_bounds__(THREADS, 2) void dice_count_kernel(
    const int* __restrict__ pred, const int* __restrict__ targ,
    unsigned int* __restrict__ partial) {
  const int b = blockIdx.y;
  // Wave-uniform 64-bit bases (SGPRs via "s" constraint); per-thread part in voffset.
  const unsigned long long pB = (unsigned long long)(
      pred + (long long)b * NPB + (long long)blockIdx.x * (THREADS * VECS * 4));
  const unsigned long long tB = (unsigned long long)(
      targ + (long long)b * NPB + (long long)blockIdx.x * (THREADS * VECS * 4));

  const unsigned vo0 = threadIdx.x * 16u;   // lane stride 16B, coalesced

  // 4 rotating buffer pairs -> at most 8 int4 (32 VGPRs) of load data live.
  v4i pr0, pr1, pr2, pr3, tr0, tr1, tr2, tr3;

  // Packed per-lane counters: class c in bits [6c, 6c+6).
  // acc*0 <- pairs 0..7 (32 voxels <= 63/class), acc*1 <- pairs 8..15.
  unsigned accP0 = 0, accP1 = 0, accT0 = 0, accT1 = 0, accI0 = 0, accI1 = 0;

#define ACC_ELEM(PE, TE, AP, AT, AI)                   \
    {                                                  \
      const unsigned op = 1u << (6u * (unsigned)(PE)); \
      AP += op;                                        \
      AT += 1u << (6u * (unsigned)(TE));               \
      AI += ((PE) == (TE)) ? op : 0u;                  \
    }
#define CONS1(PV, TV, AP, AT, AI)                      \
    ACC_ELEM(PV[0], TV[0], AP, AT, AI)                 \
    ACC_ELEM(PV[1], TV[1], AP, AT, AI)                 \
    ACC_ELEM(PV[2], TV[2], AP, AT, AI)                 \
    ACC_ELEM(PV[3], TV[3], AP, AT, AI)

#define ISSUE(BUF, K) \
    GLOAD(pr##BUF, vo0 + (K) * 4096u, pB); \
    GLOAD(tr##BUF, vo0 + (K) * 4096u, tB)
#define STEP(BUF, N, AP, AT, AI) \
    WAITP(N, pr##BUF, tr##BUF);  \
    CONS1(pr##BUF, tr##BUF, AP, AT, AI)

  // Prologue: 4 pairs (8 loads, 8 KB) in flight.
  ISSUE(0, 0); ISSUE(1, 1); ISSUE(2, 2); ISSUE(3, 3);
  // Steady state: wait for oldest pair (6 younger loads outstanding),
  // consume it, refill the freed buffer with the pair 4 ahead.
  STEP(0, 6, accP0, accT0, accI0); ISSUE(0, 4);
  STEP(1, 6, accP0, accT0, accI0); ISSUE(1, 5);
  STEP(2, 6, accP0, accT0, accI0); ISSUE(2, 6);
  STEP(3, 6, accP0, accT0, accI0); ISSUE(3, 7);
  STEP(0, 6, accP0, accT0, accI0); ISSUE(0, 8);
  STEP(1, 6, accP0, accT0, accI0); ISSUE(1, 9);
  STEP(2, 6, accP0, accT0, accI0); ISSUE(2, 10);
  STEP(3, 6, accP0, accT0, accI0); ISSUE(3, 11);
  STEP(0, 6, accP1, accT1, accI1); ISSUE(0, 12);
  STEP(1, 6, accP1, accT1, accI1); ISSUE(1, 13);
  STEP(2, 6, accP1, accT1, accI1); ISSUE(2, 14);
  STEP(3, 6, accP1, accT1, accI1); ISSUE(3, 15);
  // Drain: pairs 12..15.
  STEP(0, 6, accP1, accT1, accI1);
  STEP(1, 4, accP1, accT1, accI1);
  STEP(2, 2, accP1, accT1, accI1);
  STEP(3, 0, accP1, accT1, accI1);

  // Unpack 6-bit fields of both halves -> 16-bit pairs (per-field <= 64).
#define UNPACK(A0, A1, R01, R23, R4)                                     \
  unsigned R01 = ((A0 & 63u) + (A1 & 63u)) |                             \
                 ((((A0 >> 6) & 63u) + ((A1 >> 6) & 63u)) << 16);        \
  unsigned R23 = (((A0 >> 12) & 63u) + ((A1 >> 12) & 63u)) |             \
                 ((((A0 >> 18) & 63u) + ((A1 >> 18) & 63u)) << 16);      \
  unsigned R4 = ((A0 >> 24) & 63u) + ((A1 >> 24) & 63u);
  UNPACK(accP0, accP1, p01, p23, p4r)
  UNPACK(accT0, accT1, t01, t23, t4r)
  UNPACK(accI0, accI1, i01, i23, i4r)

  // 64-lane butterfly; 16-bit fields hold <= 64*64 = 4096, no overflow.
#pragma unroll
  for (int off = 32; off >= 1; off >>= 1) {
    p01 += (unsigned)__shfl_xor((int)p01, off);
    p23 += (unsigned)__shfl_xor((int)p23, off);
    p4r += (unsigned)__shfl_xor((int)p4r, off);
    t01 += (unsigned)__shfl_xor((int)t01, off);
    t23 += (unsigned)__shfl_xor((int)t23, off);
    t4r += (unsigned)__shfl_xor((int)t4r, off);
    i01 += (unsigned)__shfl_xor((int)i01, off);
    i23 += (unsigned)__shfl_xor((int)i23, off);
    i4r += (unsigned)__shfl_xor((int)i4r, off);
  }

  __shared__ unsigned int s[SLOTS];
  if (threadIdx.x < SLOTS) s[threadIdx.x] = 0;
  __syncthreads();

  if ((threadIdx.x & 63) == 0) {
    atomicAdd(&s[0], p01 & 0xFFFFu);
    atomicAdd(&s[1], p01 >> 16);
    atomicAdd(&s[2], p23 & 0xFFFFu);
    atomicAdd(&s[3], p23 >> 16);
    atomicAdd(&s[4], p4r);
    atomicAdd(&s[5], t01 & 0xFFFFu);
    atomicAdd(&s[6], t01 >> 16);
    atomicAdd(&s[7], t23 & 0xFFFFu);
    atomicAdd(&s[8], t23 >> 16);
    atomicAdd(&s[9], t4r);
    atomicAdd(&s[10], i01 & 0xFFFFu);
    atomicAdd(&s[11], i01 >> 16);
    atomicAdd(&s[12], i23 & 0xFFFFu);
    atomicAdd(&s[13], i23 >> 16);
    atomicAdd(&s[14], i4r);
  }
  __syncthreads();

  if (threadIdx.x < SLOTS)
    partial[(b * BLOCKS_X + blockIdx.x) * PSTRIDE + threadIdx.x] = s[threadIdx.x];
}

__global__ __launch_bounds__(256) void dice_final_kernel(
    const unsigned int* __restrict__ partial, float* __restrict__ out) {
  // 240 active threads: t = (bb*SLOTS + slot)*4 + q; q splits the 256 blocks
  // of one batch into quarters for parallel latency hiding.
  __shared__ unsigned int red[BATCH * SLOTS][4];
  const int t = threadIdx.x;
  if (t < BATCH * SLOTS * 4) {
    const int q = t & 3;
    const int s = (t >> 2) % SLOTS;
    const int bb = (t >> 2) / SLOTS;
    unsigned int sum = 0;
    for (int j = q * (BLOCKS_X / 4); j < (q + 1) * (BLOCKS_X / 4); ++j)
      sum += partial[(bb * BLOCKS_X + j) * PSTRIDE + s];
    red[(t >> 2)][q] = sum;
  }
  __syncthreads();
  if (t < NUM_CLASSES) {
    float acc = 0.0f;
#pragma unroll
    for (int bb = 0; bb < BATCH; ++bb) {
      const int ip = bb * SLOTS + t;
      const int it = bb * SLOTS + 5 + t;
      const int ii = bb * SLOTS + 10 + t;
      const float ps = (float)(red[ip][0] + red[ip][1] + red[ip][2] + red[ip][3]);
      const float ts = (float)(red[it][0] + red[it][1] + red[it][2] + red[it][3]);
      const float is = (float)(red[ii][0] + red[ii][1] + red[ii][2] + red[ii][3]);
      float num = 2.0f * is;
      float den = ps + ts;
      if (den == 0.0f) { num = 1.0f; den = 1.0f; }
      acc += num / den;
    }
    out[t] = acc * (1.0f / BATCH);
  }
}

extern "C" void kernel_launch(void* const* d_in, const int* in_sizes, int n_in,
                              void* d_out, int out_size, void* d_ws, size_t ws_size,
                              hipStream_t stream) {
  const int* pred = (const int*)d_in[0];
  const int* targ = (const int*)d_in[1];
  float* out = (float*)d_out;
  unsigned int* partial = (unsigned int*)d_ws;

  dim3 grid(BLOCKS_X, BATCH);
  dice_count_kernel<<<grid, THREADS, 0, stream>>>(pred, targ, partial);
  dice_final_kernel<<<1, 256, 0, stream>>>(partial, out);
}

// Round 6
// 149.351 us; speedup vs baseline: 1.0071x; 1.0008x over previous
//
#include <hip/hip_runtime.h>

#define NUM_CLASSES 5
#define BATCH 4
#define NPB (64 * 256 * 256)            // voxels per batch = 4,194,304
#define VEC_PER_BATCH (NPB / 4)         // int4 vectors per batch = 1,048,576
#define THREADS 256
#define VECS 16                         // int4 per thread per input (64 voxels)
#define BLOCKS_X (VEC_PER_BATCH / (THREADS * VECS))   // 256 per batch
#define SLOTS 15                        // 5 pred, 5 targ, 5 inter
#define PSTRIDE 16                      // padded per-block partial stride
#define DEPTH 4                         // staging rounds in flight per wave

// Round-6 theory: seven identical ~45.5us results; every VGPR-landing-zone
// pipeline (plain loads, named buffers, asm 16-deep, asm 4-buffer) was
// serialized by the register allocator (VGPR_Count 32/40/52/40/24 -- never
// the 64+ the pipeline needs). Fix: change the landing zone. global_load_lds
// DMAs 16B/lane straight to LDS -- zero VGPRs in flight, so pipeline depth
// is a property of the instruction stream, not the RA. Per-wave-private
// staging buffers (each wave reads back only its own DMA) -> correctness
// needs only the wave's own counted s_waitcnt vmcnt, no barriers.
// Depth 4 rounds x 2 ops = 8 loads (8KB) in flight/wave; 16 waves/CU ->
// 128KB in flight/CU vs ~1-2KB in rounds 0-5. Slot-reuse safety: the
// accumulate forces lgkmcnt(0) before its VALU uses, which precede the
// re-STAGE in program order; in-order wave issue => DMA cannot overwrite
// LDS before the ds_read data is in registers. sched_barrier(0) pins order.

typedef int v4i __attribute__((ext_vector_type(4)));

__device__ __forceinline__ void gload_lds16(const int* gp, int* lp) {
  __builtin_amdgcn_global_load_lds(
      (const __attribute__((address_space(1))) void*)gp,
      (__attribute__((address_space(3))) void*)lp, 16, 0, 0);
}

#define WAITN(N) asm volatile("s_waitcnt vmcnt(" #N ")" ::: "memory")

__global__ __launch_bounds__(THREADS, 4) void dice_count_kernel(
    const int* __restrict__ pred, const int* __restrict__ targ,
    unsigned int* __restrict__ partial) {
  const int b = blockIdx.y;
  const int tid = threadIdx.x;
  const int w = tid >> 6;          // wave id 0..3
  const int lane = tid & 63;

  const int* pB = pred + (long long)b * NPB +
                  (long long)blockIdx.x * (THREADS * VECS * 4);
  const int* tB = targ + (long long)b * NPB +
                  (long long)blockIdx.x * (THREADS * VECS * 4);

  // Per-wave staging: [wave][slot][pred|targ][256 ints = 1KB]. 32 KB total.
  // DMA dest is wave-uniform base; HW writes base + lane*16 -> lane l owns
  // ints [4l, 4l+4), exactly what it reads back.
  __shared__ int stage[4][DEPTH][2][256];

  // Packed per-lane counters: class c in bits [6c, 6c+6).
  // acc*0 <- rounds 0..7 (32 voxels <= 63/class), acc*1 <- rounds 8..15.
  unsigned accP0 = 0, accP1 = 0, accT0 = 0, accT1 = 0, accI0 = 0, accI1 = 0;

#define STAGE(R)                                                        \
  gload_lds16(pB + ((R) * THREADS + tid) * 4,                           \
              &stage[w][(R) & (DEPTH - 1)][0][0]);                      \
  gload_lds16(tB + ((R) * THREADS + tid) * 4,                           \
              &stage[w][(R) & (DEPTH - 1)][1][0]);

#define ACC_ELEM(PE, TE, AP, AT, AI)                   \
    {                                                  \
      const unsigned op = 1u << (6u * (unsigned)(PE)); \
      AP += op;                                        \
      AT += 1u << (6u * (unsigned)(TE));               \
      AI += ((PE) == (TE)) ? op : 0u;                  \
    }

#define CONSUME(R, AP, AT, AI)                                          \
  {                                                                     \
    const v4i pv = *(const v4i*)&stage[w][(R) & (DEPTH - 1)][0][lane * 4]; \
    const v4i tv = *(const v4i*)&stage[w][(R) & (DEPTH - 1)][1][lane * 4]; \
    ACC_ELEM(pv[0], tv[0], AP, AT, AI)                                  \
    ACC_ELEM(pv[1], tv[1], AP, AT, AI)                                  \
    ACC_ELEM(pv[2], tv[2], AP, AT, AI)                                  \
    ACC_ELEM(pv[3], tv[3], AP, AT, AI)                                  \
  }

  // Prologue: 4 rounds (8 DMA ops, 8 KB) in flight for this wave.
  STAGE(0) STAGE(1) STAGE(2) STAGE(3)

  // Steady state r=0..11: round r landed when vmcnt<=6 (rounds r+1..r+3
  // outstanding). Consume, then refill slot with round r+4.
#define STEP(R, AP, AT, AI)                      \
  WAITN(6);                                      \
  CONSUME(R, AP, AT, AI)                         \
  __builtin_amdgcn_sched_barrier(0);             \
  STAGE(R + 4)

  STEP(0, accP0, accT0, accI0)
  STEP(1, accP0, accT0, accI0)
  STEP(2, accP0, accT0, accI0)
  STEP(3, accP0, accT0, accI0)
  STEP(4, accP0, accT0, accI0)
  STEP(5, accP0, accT0, accI0)
  STEP(6, accP0, accT0, accI0)
  STEP(7, accP0, accT0, accI0)
  STEP(8, accP1, accT1, accI1)
  STEP(9, accP1, accT1, accI1)
  STEP(10, accP1, accT1, accI1)
  STEP(11, accP1, accT1, accI1)
  // Drain: rounds 12..15, no more issues.
  WAITN(6); CONSUME(12, accP1, accT1, accI1)
  WAITN(4); CONSUME(13, accP1, accT1, accI1)
  WAITN(2); CONSUME(14, accP1, accT1, accI1)
  WAITN(0); CONSUME(15, accP1, accT1, accI1)

  // Unpack 6-bit fields of both halves -> 16-bit pairs (per-field <= 64).
#define UNPACK(A0, A1, R01, R23, R4)                                     \
  unsigned R01 = ((A0 & 63u) + (A1 & 63u)) |                             \
                 ((((A0 >> 6) & 63u) + ((A1 >> 6) & 63u)) << 16);        \
  unsigned R23 = (((A0 >> 12) & 63u) + ((A1 >> 12) & 63u)) |             \
                 ((((A0 >> 18) & 63u) + ((A1 >> 18) & 63u)) << 16);      \
  unsigned R4 = ((A0 >> 24) & 63u) + ((A1 >> 24) & 63u);
  UNPACK(accP0, accP1, p01, p23, p4r)
  UNPACK(accT0, accT1, t01, t23, t4r)
  UNPACK(accI0, accI1, i01, i23, i4r)

  // 64-lane butterfly; 16-bit fields hold <= 64*64 = 4096, no overflow.
#pragma unroll
  for (int off = 32; off >= 1; off >>= 1) {
    p01 += (unsigned)__shfl_xor((int)p01, off);
    p23 += (unsigned)__shfl_xor((int)p23, off);
    p4r += (unsigned)__shfl_xor((int)p4r, off);
    t01 += (unsigned)__shfl_xor((int)t01, off);
    t23 += (unsigned)__shfl_xor((int)t23, off);
    t4r += (unsigned)__shfl_xor((int)t4r, off);
    i01 += (unsigned)__shfl_xor((int)i01, off);
    i23 += (unsigned)__shfl_xor((int)i23, off);
    i4r += (unsigned)__shfl_xor((int)i4r, off);
  }

  __shared__ unsigned int s[SLOTS];
  if (threadIdx.x < SLOTS) s[threadIdx.x] = 0;
  __syncthreads();

  if ((threadIdx.x & 63) == 0) {
    atomicAdd(&s[0], p01 & 0xFFFFu);
    atomicAdd(&s[1], p01 >> 16);
    atomicAdd(&s[2], p23 & 0xFFFFu);
    atomicAdd(&s[3], p23 >> 16);
    atomicAdd(&s[4], p4r);
    atomicAdd(&s[5], t01 & 0xFFFFu);
    atomicAdd(&s[6], t01 >> 16);
    atomicAdd(&s[7], t23 & 0xFFFFu);
    atomicAdd(&s[8], t23 >> 16);
    atomicAdd(&s[9], t4r);
    atomicAdd(&s[10], i01 & 0xFFFFu);
    atomicAdd(&s[11], i01 >> 16);
    atomicAdd(&s[12], i23 & 0xFFFFu);
    atomicAdd(&s[13], i23 >> 16);
    atomicAdd(&s[14], i4r);
  }
  __syncthreads();

  if (threadIdx.x < SLOTS)
    partial[(b * BLOCKS_X + blockIdx.x) * PSTRIDE + threadIdx.x] = s[threadIdx.x];
}

__global__ __launch_bounds__(256) void dice_final_kernel(
    const unsigned int* __restrict__ partial, float* __restrict__ out) {
  // 240 active threads: t = (bb*SLOTS + slot)*4 + q; q splits the 256 blocks
  // of one batch into quarters for parallel latency hiding.
  __shared__ unsigned int red[BATCH * SLOTS][4];
  const int t = threadIdx.x;
  if (t < BATCH * SLOTS * 4) {
    const int q = t & 3;
    const int s = (t >> 2) % SLOTS;
    const int bb = (t >> 2) / SLOTS;
    unsigned int sum = 0;
    for (int j = q * (BLOCKS_X / 4); j < (q + 1) * (BLOCKS_X / 4); ++j)
      sum += partial[(bb * BLOCKS_X + j) * PSTRIDE + s];
    red[(t >> 2)][q] = sum;
  }
  __syncthreads();
  if (t < NUM_CLASSES) {
    float acc = 0.0f;
#pragma unroll
    for (int bb = 0; bb < BATCH; ++bb) {
      const int ip = bb * SLOTS + t;
      const int it = bb * SLOTS + 5 + t;
      const int ii = bb * SLOTS + 10 + t;
      const float ps = (float)(red[ip][0] + red[ip][1] + red[ip][2] + red[ip][3]);
      const float ts = (float)(red[it][0] + red[it][1] + red[it][2] + red[it][3]);
      const float is = (float)(red[ii][0] + red[ii][1] + red[ii][2] + red[ii][3]);
      float num = 2.0f * is;
      float den = ps + ts;
      if (den == 0.0f) { num = 1.0f; den = 1.0f; }
      acc += num / den;
    }
    out[t] = acc * (1.0f / BATCH);
  }
}

extern "C" void kernel_launch(void* const* d_in, const int* in_sizes, int n_in,
                              void* d_out, int out_size, void* d_ws, size_t ws_size,
                              hipStream_t stream) {
  const int* pred = (const int*)d_in[0];
  const int* targ = (const int*)d_in[1];
  float* out = (float*)d_out;
  unsigned int* partial = (unsigned int*)d_ws;

  dim3 grid(BLOCKS_X, BATCH);
  dice_count_kernel<<<grid, THREADS, 0, stream>>>(pred, targ, partial);
  dice_final_kernel<<<1, 256, 0, stream>>>(partial, out);
}